// Round 1
// baseline (13217.667 us; speedup 1.0000x reference)
//
#include <hip/hip_runtime.h>
#include <math.h>

#define TLEN   131072
#define NFFT   1024
#define HOP    512
#define NFRAMES 256
#define NFREQ  513
#define NEG_SLOPE 0.2f

// ---------------------------------------------------------------------------
// STFT: one block per frame. Builds hann-windowed frame + twiddle tables in
// LDS, each thread computes bins k = tid, tid+256 (+512 for tid 0), then a
// block max-reduce normalizes the frame.
// ---------------------------------------------------------------------------
__global__ __launch_bounds__(256) void stft_kernel(const float* __restrict__ x,
                                                   float* __restrict__ spec) {
    __shared__ float xw[NFFT];
    __shared__ float ct[NFFT];
    __shared__ float st[NFFT];
    __shared__ float wmax[4];

    const int tid  = threadIdx.x;
    const int bid  = blockIdx.x;
    const int b    = bid >> 8;    // / NFRAMES
    const int fr   = bid & 255;   // % NFRAMES
    const int base = fr * HOP;
    const float* xb = x + (size_t)b * TLEN;

    const float step = 6.28318530717958647692f / (float)NFFT;
    for (int n = tid; n < NFFT; n += 256) {
        int gi = base + n;
        float v = (gi < TLEN) ? xb[gi] : 0.0f;
        float s, c;
        sincosf(step * (float)n, &s, &c);
        ct[n] = c;
        st[n] = s;
        xw[n] = v * (0.5f - 0.5f * c);   // hann window shares the same cosine
    }
    __syncthreads();

    float mag[3];
    int   nk = 0;
    float lmax = 0.0f;
    for (int k = tid; k <= NFFT / 2; k += 256) {
        float re = 0.0f, im = 0.0f;
        int t = 0;
        #pragma unroll 4
        for (int n = 0; n < NFFT; ++n) {
            float v = xw[n];
            re = fmaf(v, ct[t], re);
            im = fmaf(v, st[t], im);
            t = (t + k) & (NFFT - 1);
        }
        float m = sqrtf(re * re + im * im);
        mag[nk++] = m;
        lmax = fmaxf(lmax, m);
    }

    // wave (64-lane) max reduce, then cross-wave via LDS
    #pragma unroll
    for (int off = 32; off > 0; off >>= 1)
        lmax = fmaxf(lmax, __shfl_xor(lmax, off));
    if ((tid & 63) == 0) wmax[tid >> 6] = lmax;
    __syncthreads();
    float mx = fmaxf(fmaxf(wmax[0], wmax[1]), fmaxf(wmax[2], wmax[3]));

    float* so = spec + (size_t)bid * NFREQ;
    nk = 0;
    for (int k = tid; k <= NFFT / 2; k += 256)
        so[k] = mag[nk++] / mx;
}

// ---------------------------------------------------------------------------
// Generic direct NHWC conv2d (+ optional leaky relu). One thread per output
// element. Geometry is template-specialized so the ci loop fully unrolls.
//   in : [B, IH, IW, CI]      w : [KH, KW, WCI, CO]  (HWIO)
//   out: [B, OH, OW, CO]      strideH == 1 always, dilW == 1 always.
// CI may be < WCI (conv0: imaginary input channel is all-zero -> skipped).
// ---------------------------------------------------------------------------
template<int KH, int KW, int CI, int WCI, int CO, int SW, int DH, int PH, int PW, int LR>
__global__ __launch_bounds__(256) void conv_kernel(
    const float* __restrict__ in, const float* __restrict__ w,
    const float* __restrict__ bias, float* __restrict__ out,
    int B, int IH, int IW, int OH, int OW)
{
    const unsigned total = (unsigned)B * (unsigned)OH * (unsigned)OW * (unsigned)CO;
    unsigned idx = blockIdx.x * 256u + threadIdx.x;
    if (idx >= total) return;

    const int oc = (int)(idx % (unsigned)CO);
    unsigned t  = idx / (unsigned)CO;
    const int ow = (int)(t % (unsigned)OW); t /= (unsigned)OW;
    const int oh = (int)(t % (unsigned)OH);
    const int b  = (int)(t / (unsigned)OH);

    float acc = bias[oc];
    const float* inb = in + (size_t)b * IH * IW * CI;

    for (int kh = 0; kh < KH; ++kh) {
        const int ih = oh + kh * DH - PH;
        if (ih < 0 || ih >= IH) continue;
        const float* inr = inb + (size_t)ih * IW * CI;
        for (int kw = 0; kw < KW; ++kw) {
            const int iw = ow * SW + kw - PW;
            if (iw < 0 || iw >= IW) continue;
            const float* ip  = inr + (size_t)iw * CI;
            const float* wp2 = w + ((size_t)(kh * KW + kw) * WCI) * CO + oc;
            #pragma unroll
            for (int ci = 0; ci < CI; ++ci)
                acc = fmaf(ip[ci], wp2[(size_t)ci * CO], acc);
        }
    }
    if (LR) acc = (acc >= 0.0f) ? acc : NEG_SLOPE * acc;
    out[idx] = acc;
}

// ---------------------------------------------------------------------------
// Launch
// ---------------------------------------------------------------------------
extern "C" void kernel_launch(void* const* d_in, const int* in_sizes, int n_in,
                              void* d_out, int out_size, void* d_ws, size_t ws_size,
                              hipStream_t stream) {
    const float* x  = (const float*)d_in[0];
    const float* w0 = (const float*)d_in[1];
    const float* b0 = (const float*)d_in[2];
    const float* w1 = (const float*)d_in[3];
    const float* b1 = (const float*)d_in[4];
    const float* w2 = (const float*)d_in[5];
    const float* b2 = (const float*)d_in[6];
    const float* w3 = (const float*)d_in[7];
    const float* b3 = (const float*)d_in[8];
    const float* w4 = (const float*)d_in[9];
    const float* b4 = (const float*)d_in[10];
    const float* wp = (const float*)d_in[11];
    const float* bp = (const float*)d_in[12];

    float* out = (float*)d_out;
    // output layout: z, fmap0..fmap4, concatenated flat in return order
    float* z  = out;                      // 16*256*65*1   =    266,240
    float* f0 = z  +    266240;           // 16*256*513*32 = 67,239,936
    float* f1 = f0 + 67239936;            // 16*256*257*32 = 33,685,504
    float* f2 = f1 + 33685504;            // 16*256*129*32 = 16,908,288
    float* f3 = f2 + 16908288;            // 16*256*65*32  =  8,519,680
    float* f4 = f3 +  8519680;            // 16*256*65*32  =  8,519,680

    // Park the normalized spectrum (16*256*513 = 2,101,248 f32) in the fmap4
    // slot; conv0 consumes it long before conv4 overwrites the region.
    float* spec = f4;

    stft_kernel<<<16 * NFRAMES, 256, 0, stream>>>(x, spec);

    // conv0: [16,256,513,1(of 2)] -> [16,256,513,32], k3x9 pad(1,4)
    conv_kernel<3, 9, 1, 2, 32, 1, 1, 1, 4, 1>
        <<<67239936u / 256, 256, 0, stream>>>(spec, w0, b0, f0, 16, 256, 513, 256, 513);

    // conv1: stride(1,2) dil(1,1) pad(1,4): [16,256,513,32] -> [16,256,257,32]
    conv_kernel<3, 9, 32, 32, 32, 2, 1, 1, 4, 1>
        <<<33685504u / 256, 256, 0, stream>>>(f0, w1, b1, f1, 16, 256, 513, 256, 257);

    // conv2: stride(1,2) dil(2,1) pad(2,4): -> [16,256,129,32]
    conv_kernel<3, 9, 32, 32, 32, 2, 2, 2, 4, 1>
        <<<16908288u / 256, 256, 0, stream>>>(f1, w2, b2, f2, 16, 256, 257, 256, 129);

    // conv3: stride(1,2) dil(4,1) pad(4,4): -> [16,256,65,32]
    conv_kernel<3, 9, 32, 32, 32, 2, 4, 4, 4, 1>
        <<<8519680u / 256, 256, 0, stream>>>(f2, w3, b3, f3, 16, 256, 129, 256, 65);

    // conv4: k3x3 pad(1,1): -> [16,256,65,32]   (overwrites spec region - OK)
    conv_kernel<3, 3, 32, 32, 32, 1, 1, 1, 1, 1>
        <<<8519680u / 256, 256, 0, stream>>>(f3, w4, b4, f4, 16, 256, 65, 256, 65);

    // post conv: k3x3 pad(1,1), CO=1, no lrelu: -> [16,256,65,1]
    conv_kernel<3, 3, 32, 32, 1, 1, 1, 1, 1, 0>
        <<<266240u / 256, 256, 0, stream>>>(f4, wp, bp, z, 16, 256, 65, 256, 65);
}